// Round 3
// baseline (803.574 us; speedup 1.0000x reference)
//
#include <hip/hip_runtime.h>
#include <cstddef>

#define CC   128
#define LDIM 361
#define MDIM 361
#define KDIM 361
#define NLON 720
#define LP   384          // padded l (stage A K-dim)
#define MRP  736          // padded mr (stage B K-dim)
#define NP   768          // padded n (stage B N-dim)
#define CK   (CC*KDIM)    // 46208
#define CR   (2*CC)       // 256
#define MR2  722          // real mr count

typedef __attribute__((ext_vector_type(8))) short short8;
typedef __attribute__((ext_vector_type(4))) float floatx4;

__device__ __forceinline__ unsigned short f2bf(float f) {
    union { float f; unsigned u; } v; v.f = f;
    unsigned u = v.u;
    u += 0x7fffu + ((u >> 16) & 1u);   // RNE
    return (unsigned short)(u >> 16);
}

__device__ __forceinline__ void async_copy16(const void* g, void* l) {
    __builtin_amdgcn_global_load_lds(
        (const __attribute__((address_space(1))) void*)g,
        (__attribute__((address_space(3))) void*)l, 16, 0, 0);
}

// ---------------------------------------------------------------------------
// Tp[n][mr] bf16; pad rows/cols zero.
__global__ void sht_gen_T(unsigned short* __restrict__ Tp) {
    int idx = blockIdx.x * 256 + threadIdx.x;
    if (idx >= NP * MRP) return;
    int n = idx / MRP, mr = idx - n * MRP;
    float v = 0.f;
    if (n < NLON && mr < MR2) {
        int m = mr >> 1, im = mr & 1;
        if (m == 0)            v = im ? 0.f : 1.f;
        else if (m == MDIM-1)  v = im ? 0.f : ((n & 1) ? -1.f : 1.f);
        else {
            int ph = (m * n) % NLON;
            float ang = (float)ph * (float)(3.14159265358979323846 / 360.0);
            v = im ? (-2.f * sinf(ang)) : (2.f * cosf(ang));
        }
    }
    Tp[idx] = f2bf(v);
}

// ---------------------------------------------------------------------------
// x fp32 [c][l][m][r] -> xA bf16 [m][cr=2c+r][LP]  (l-fast, zero pad l>=361)
__global__ __launch_bounds__(256)
void sht_prep_x(const float* __restrict__ x, unsigned short* __restrict__ xA) {
    __shared__ float2 tile[64][33];    // [l][m]
    const int mt = blockIdx.x;         // 0..11
    const int lt = blockIdx.y;         // 0..5
    const int c  = blockIdx.z;         // 0..127
    const int t  = threadIdx.x;

    #pragma unroll
    for (int u = 0; u < 8; ++u) {
        int p  = t + 256 * u;
        int li = p >> 5, mi = p & 31;
        int l = lt * 64 + li, m = mt * 32 + mi;
        float2 v = make_float2(0.f, 0.f);
        if (l < LDIM && m < MDIM)
            v = *(const float2*)(x + ((size_t)(c * LDIM + l) * MDIM + m) * 2);
        tile[li][mi] = v;
    }
    __syncthreads();

    #pragma unroll
    for (int u = 0; u < 2; ++u) {
        int s  = t + 256 * u;          // 0..511
        int mi = s >> 4, rr = (s >> 3) & 1, lo = (s & 7) * 8;
        int m = mt * 32 + mi;
        if (m >= MDIM) continue;
        short8 h;
        #pragma unroll
        for (int e = 0; e < 8; ++e) {
            float2 p = tile[lo + e][mi];
            h[e] = (short)f2bf(rr ? p.y : p.x);
        }
        *(short8*)(xA + ((size_t)m * CR + 2 * c + rr) * LP + lt * 64 + lo) = h;
    }
}

// ---------------------------------------------------------------------------
// Stage A: per-m GEMM  D[cr][k] = sum_l xA[m][cr][l] * pct[m][l][k]
// M=256 (all cr), N=128 (kt tile), BK=32. Output xs2[2m+r][c*KDIM+k] (ck-fast).
__global__ __launch_bounds__(256)
void sht_stageA(const float* __restrict__ pct, const unsigned short* __restrict__ xA,
                unsigned short* __restrict__ xs2) {
    __shared__ unsigned short As[256 * 32];   // [cr][lq][8]  16 KB
    __shared__ unsigned short Bs[128 * 40];   // [k][l] l-fast, pad 40  10 KB

    const int m  = blockIdx.y;
    const int kt = blockIdx.x;                // 0..2
    const int t  = threadIdx.x;
    const int w  = t >> 6, L = t & 63;
    const int lane15 = L & 15, quad = L >> 4;
    const int tl = t >> 3;                    // 0..31 : l within tile (B staging)
    const int tk = (t & 7) * 4;               // B staging k base

    const unsigned short* xAm = xA + (size_t)m * CR * LP;
    const float* pctm = pct + (size_t)m * LDIM * KDIM + (size_t)kt * 128;

    floatx4 acc[4][8] = {};

    for (int kb = 0; kb < LP; kb += 32) {
        // A tile: 256 cr x 32 l via async copy (16 x 1KB wave-issues)
        #pragma unroll
        for (int i = 0; i < 4; ++i) {
            int s = (w * 4 + i) * 64 + L;
            int cr = s >> 2, lq = s & 3;
            async_copy16(xAm + (size_t)cr * LP + kb + lq * 8,
                         As + (size_t)(w * 4 + i) * 64 * 8);
        }
        // B tile: pct rows (k-fast fp32) -> LDS [k][l] l-fast bf16
        {
            int l = kb + tl;
            bool lok = (l < LDIM);
            const float* prow = pctm + (size_t)l * KDIM;
            #pragma unroll
            for (int u = 0; u < 4; ++u) {
                int kc = tk + u * 32;          // col in tile (0..127)
                int kg = kt * 128 + kc;        // global k
                #pragma unroll
                for (int j = 0; j < 4; ++j) {
                    float f = (lok && (kg + j) < KDIM) ? prow[kc + j] : 0.f;
                    Bs[(kc + j) * 40 + tl] = f2bf(f);
                }
            }
        }
        __syncthreads();

        short8 af[4];
        #pragma unroll
        for (int i = 0; i < 4; ++i)
            af[i] = *(const short8*)&As[((w * 64 + i * 16 + lane15) * 4 + quad) * 8];
        #pragma unroll
        for (int jf = 0; jf < 8; ++jf) {
            short8 bf = *(const short8*)&Bs[(jf * 16 + lane15) * 40 + quad * 8];
            #pragma unroll
            for (int i = 0; i < 4; ++i)
                acc[i][jf] = __builtin_amdgcn_mfma_f32_16x16x32_bf16(af[i], bf, acc[i][jf], 0, 0, 0);
        }
        __syncthreads();
    }

    // epilogue: (cr,k) -> xs2[(2m+r)*CK + c*KDIM + k]; 16-lane groups give 32B runs
    #pragma unroll
    for (int i = 0; i < 4; ++i) {
        #pragma unroll
        for (int jf = 0; jf < 8; ++jf) {
            int k = kt * 128 + jf * 16 + lane15;
            if (k >= KDIM) continue;
            #pragma unroll
            for (int e = 0; e < 4; ++e) {
                int cr = w * 64 + i * 16 + quad * 4 + e;
                int c = cr >> 1, r = cr & 1;
                xs2[(size_t)(2 * m + r) * CK + (size_t)c * KDIM + k] = f2bf(acc[i][jf][e]);
            }
        }
    }
}

// ---------------------------------------------------------------------------
// Transpose xs2[mr][ck] -> xs[ck][MRP], zero pad mr>=722. 64x64 LDS tiles.
__global__ __launch_bounds__(256)
void sht_transpose(const unsigned short* __restrict__ xs2, unsigned short* __restrict__ xs) {
    __shared__ unsigned short tile[64 * 72];  // pad 72 (stride 144B, 16B-aligned)
    const int bk = blockIdx.x;   // ck tile 0..721
    const int mt = blockIdx.y;   // 0..11  (covers mr 0..767, writes clipped at 736)
    const int t  = threadIdx.x;

    #pragma unroll
    for (int u = 0; u < 2; ++u) {
        int s = t + 256 * u;
        int row = s >> 3, col8 = (s & 7) * 8;
        int mr = mt * 64 + row;
        short8 v = {};
        if (mr < MR2)
            v = *(const short8*)(xs2 + (size_t)mr * CK + bk * 64 + col8);
        *(short8*)&tile[row * 72 + col8] = v;
    }
    __syncthreads();

    #pragma unroll
    for (int u = 0; u < 2; ++u) {
        int s = t + 256 * u;
        int cki = s >> 3, mo = (s & 7) * 8;
        int mro = mt * 64 + mo;
        if (mro >= MRP) continue;
        short8 h;
        #pragma unroll
        for (int e = 0; e < 8; ++e) h[e] = tile[(mo + e) * 72 + cki];
        *(short8*)(xs + (size_t)(bk * 64 + cki) * MRP + mro) = h;
    }
}

// ---------------------------------------------------------------------------
// Stage B: out[ck][j] = sum_mr xs[ck][mr] * Tp[j][mr]
__global__ __launch_bounds__(256)
void sht_stageB(const unsigned short* __restrict__ xs, const unsigned short* __restrict__ Tp,
                float* __restrict__ out) {
    __shared__ unsigned short As[128 * 32];   // [ck][mq][8] 8KB
    __shared__ unsigned short Bs[128 * 32];   // [n][mq][8]  8KB

    const int nt  = blockIdx.x;               // 0..5
    const int ckt = blockIdx.y;               // 0..360
    const int ck0 = ckt * 128, n0 = nt * 128;
    const int t   = threadIdx.x;
    const int w   = t >> 6, L = t & 63;
    const int wr  = w & 1, wc = w >> 1;
    const int lane15 = L & 15, quad = L >> 4;

    floatx4 acc[4][4] = {};

    for (int kb = 0; kb < MRP; kb += 32) {
        #pragma unroll
        for (int i = 0; i < 2; ++i) {
            int s = w * 128 + i * 64 + L;
            int rr = s >> 2, mq = s & 3;
            async_copy16(xs + (size_t)(ck0 + rr) * MRP + kb + mq * 8,
                         As + (size_t)(w * 128 + i * 64) * 8);
            async_copy16(Tp + (size_t)(n0 + rr) * MRP + kb + mq * 8,
                         Bs + (size_t)(w * 128 + i * 64) * 8);
        }
        __syncthreads();

        short8 af[4], bfr[4];
        #pragma unroll
        for (int i = 0; i < 4; ++i)
            af[i] = *(const short8*)&As[((wr * 64 + i * 16 + lane15) * 4 + quad) * 8];
        #pragma unroll
        for (int jf = 0; jf < 4; ++jf)
            bfr[jf] = *(const short8*)&Bs[((wc * 64 + jf * 16 + lane15) * 4 + quad) * 8];
        #pragma unroll
        for (int i = 0; i < 4; ++i)
            #pragma unroll
            for (int jf = 0; jf < 4; ++jf)
                acc[i][jf] = __builtin_amdgcn_mfma_f32_16x16x32_bf16(af[i], bfr[jf], acc[i][jf], 0, 0, 0);
        __syncthreads();
    }

    #pragma unroll
    for (int i = 0; i < 4; ++i) {
        int ckr = ck0 + wr * 64 + i * 16 + quad * 4;
        #pragma unroll
        for (int jf = 0; jf < 4; ++jf) {
            int j = n0 + wc * 64 + jf * 16 + lane15;
            if (j >= NLON) continue;
            #pragma unroll
            for (int e = 0; e < 4; ++e)
                out[(size_t)(ckr + e) * NLON + j] = acc[i][jf][e];
        }
    }
}

// ---------------------------------------------------------------------------
extern "C" void kernel_launch(void* const* d_in, const int* in_sizes, int n_in,
                              void* d_out, int out_size, void* d_ws, size_t ws_size,
                              hipStream_t stream) {
    const float* x   = (const float*)d_in[0];   // [1,128,361,361,2] fp32
    const float* pct = (const float*)d_in[1];   // [361,361,361] fp32
    float* out = (float*)d_out;                 // [1,128,361,720] fp32

    // ws layout: [xs: CK*MRP bf16 = 68.0MB][xs2: 722*CK bf16 = 66.7MB]
    // Tp aliases xs2 (xs2 dead after transpose). Total 134.7MB.
    unsigned short* xs  = (unsigned short*)d_ws;
    unsigned short* xs2 = xs + (size_t)CK * MRP;
    unsigned short* Tp  = xs2;
    unsigned short* xA  = (unsigned short*)d_out;  // 71MB, dead before stage B

    sht_prep_x<<<dim3(12, 6, 128), 256, 0, stream>>>(x, xA);
    sht_stageA<<<dim3(3, MDIM), 256, 0, stream>>>(pct, xA, xs2);
    sht_transpose<<<dim3(722, 12), 256, 0, stream>>>(xs2, xs);
    sht_gen_T<<<(NP * MRP + 255) / 256, 256, 0, stream>>>(Tp);
    sht_stageB<<<dim3(6, MDIM), 256, 0, stream>>>(xs, Tp, out);
}